// Round 16
// baseline (260.900 us; speedup 1.0000x reference)
//
#include <hip/hip_runtime.h>
#include <stdint.h>

// GaitnetActor B=8192, OPT=16. Round 16: k_main + k_conv = exact R12
// (best known: k_main 135.4 us, total 239.5). k_cse re-tiled to M=8/block,
// 1024 blocks -> 4 blocks/CU = 32 waves/CU (TLP cap) for the latency-bound
// front-end chain; junk A-rows zeroed (bit-identical results).
// bf16 MFMA / fp32 accum. out[0:131072]=logits fp32, [131072:]=duration.

static constexpr int B_ = 8192;

typedef __attribute__((ext_vector_type(8))) short bf16x8;
typedef __attribute__((ext_vector_type(4))) float f32x4;

__device__ __forceinline__ float u2f(uint16_t u) {
    union { uint32_t i; float f; } c; c.i = (uint32_t)u << 16; return c.f;
}
__device__ __forceinline__ uint16_t f2u(float f) {
    union { float f; uint32_t i; } c; c.f = f;
    uint32_t x = c.i;
    return (uint16_t)((x + 0x7FFFu + ((x >> 16) & 1u)) >> 16);
}

// ws layout (uint16 elems) — identical to R12
static constexpr size_t WCSE   = 0;                    // bf16 [8192][512]
static constexpr size_t WTW1SE = 4194304;              // bf16 [512][256]
static constexpr size_t WTW1UE = WTW1SE + 131072;      // bf16 [512][128]
static constexpr size_t WTW2   = WTW1UE + 65536;       // bf16 [256][512]
static constexpr size_t WUW2   = WTW2 + 131072;        // bf16 [128][128]
static constexpr size_t WSW2   = WUW2 + 16384;         // bf16 [256][256]
static constexpr size_t WUW1B  = WSW2 + 65536;         // bf16 [128][32] 0-pad

// ---------------- k_conv: identical to R12 (404 blocks) --------------------
__global__ __launch_bounds__(256) void k_conv(
    const float* __restrict__ tw1, const float* __restrict__ tw2,
    const float* __restrict__ uw2, const float* __restrict__ sw2,
    const float* __restrict__ uw1, uint16_t* __restrict__ ws)
{
    int i4 = blockIdx.x * 256 + threadIdx.x;
    if (i4 >= 102400) {
        int q = i4 - 102400;
        int n = q >> 3, k0 = (q & 7) * 4;
        ushort4 o = {0, 0, 0, 0};
        if (k0 < 8) {
            float4 v = *reinterpret_cast<const float4*>(uw1 + n * 8 + k0);
            o.x = f2u(v.x); o.y = f2u(v.y); o.z = f2u(v.z); o.w = f2u(v.w);
        }
        *reinterpret_cast<ushort4*>(ws + WUW1B + n * 32 + k0) = o;
        return;
    }
    const float* src; size_t dst;
    if (i4 < 32768) {
        int g = i4 * 4, n = g >> 8, k = g & 255;
        src = tw1 + (size_t)n * 384 + k;
        dst = WTW1SE + (size_t)g;
    } else if (i4 < 49152) {
        int q = i4 - 32768, n = q >> 5, w = q & 31;
        src = tw1 + (size_t)n * 384 + 256 + w * 4;
        dst = WTW1UE + (size_t)n * 128 + w * 4;
    } else if (i4 < 81920) {
        int q = (i4 - 49152) * 4;
        src = tw2 + q; dst = WTW2 + q;
    } else if (i4 < 86016) {
        int q = (i4 - 81920) * 4;
        src = uw2 + q; dst = WUW2 + q;
    } else {
        int q = (i4 - 86016) * 4;
        src = sw2 + q; dst = WSW2 + q;
    }
    float4 v = *reinterpret_cast<const float4*>(src);
    ushort4 o;
    o.x = f2u(v.x); o.y = f2u(v.y); o.z = f2u(v.z); o.w = f2u(v.w);
    *reinterpret_cast<ushort4*>(ws + dst) = o;
}

// ---------------- k_cse: M=8/block, 1024 blocks, 512 thr (32 waves/CU) -----
__global__ __launch_bounds__(512) void k_cse(
    const float* __restrict__ obs,
    const float* __restrict__ sw1, const float* __restrict__ sb1,
    const float* __restrict__ sb2, const float* __restrict__ tb1,
    uint16_t* __restrict__ ws)
{
    __shared__ float xs[8][24];
    __shared__ uint16_t h1s[16 * 264];   // rows 8..15 zeroed
    __shared__ uint16_t seL[16 * 264];   // rows 8..15 zeroed
    const int t = threadIdx.x;
    const int b0 = blockIdx.x * 8;
    const uint16_t* sw2b   = ws + WSW2;
    const uint16_t* tw1seb = ws + WTW1SE;

    if (t < 176) {
        int e = t / 22, c = t - e * 22;
        xs[e][c] = obs[(size_t)(b0 + e) * 150 + c];
    }
    // zero junk rows 8..15 of h1s and seL (2112 u16 each)
    for (int i = t; i < 2112; i += 512) {
        h1s[8 * 264 + i] = 0;
        seL[8 * 264 + i] = 0;
    }
    __syncthreads();
    {   // shared L1 (VALU): neuron t&255, 4 elems each
        const int n = t & 255;
        float w[22];
        #pragma unroll
        for (int k = 0; k < 22; ++k) w[k] = sw1[n * 22 + k];
        const float bias = sb1[n];
        #pragma unroll
        for (int ii = 0; ii < 4; ++ii) {
            int e = (t >> 8) * 4 + ii;
            float a = bias;
            #pragma unroll
            for (int k = 0; k < 22; ++k) a += w[k] * xs[e][k];
            h1s[e * 264 + n] = f2u(fmaxf(a, 0.f));
        }
    }
    __syncthreads();
    const int wv = t >> 6, lane = t & 63, quad = lane >> 4, l16 = lane & 15;
    {   // shared L2 (MFMA): M=8 valid, wave N=32, K=256 -> seL
        f32x4 acc[2];
        #pragma unroll
        for (int nt = 0; nt < 2; ++nt) {
            float bv = sb2[wv * 32 + nt * 16 + l16];
            acc[nt] = {bv, bv, bv, bv};
        }
        const uint16_t* bb = sw2b + (size_t)(wv * 32 + l16) * 256 + quad * 8;
        bf16x8 bc[2], bn[2];
        bc[0] = *reinterpret_cast<const bf16x8*>(bb);
        bc[1] = *reinterpret_cast<const bf16x8*>(bb + 4096);
        #pragma unroll
        for (int kk = 0; kk < 8; ++kk) {
            if (kk < 7) {
                bn[0] = *reinterpret_cast<const bf16x8*>(bb + (kk + 1) * 32);
                bn[1] = *reinterpret_cast<const bf16x8*>(bb + 4096 + (kk + 1) * 32);
            }
            bf16x8 af = *reinterpret_cast<const bf16x8*>(
                &h1s[l16 * 264 + kk * 32 + quad * 8]);   // rows 8..15 = zeros
            #pragma unroll
            for (int nt = 0; nt < 2; ++nt)
                acc[nt] = __builtin_amdgcn_mfma_f32_16x16x32_bf16(
                    af, bc[nt], acc[nt], 0, 0, 0);
            bc[0] = bn[0]; bc[1] = bn[1];
        }
        if (quad < 2) {                                  // rows 0..7 valid
            #pragma unroll
            for (int nt = 0; nt < 2; ++nt)
                #pragma unroll
                for (int r = 0; r < 4; ++r)
                    seL[(quad * 4 + r) * 264 + wv * 32 + nt * 16 + l16] =
                        f2u(fmaxf(acc[nt][r], 0.f));
        }
    }
    __syncthreads();
    {   // cse (MFMA): M=8 valid, wave N=64, K=256, no relu -> ws
        f32x4 acc[4];
        #pragma unroll
        for (int nt = 0; nt < 4; ++nt) {
            float bv = tb1[wv * 64 + nt * 16 + l16];
            acc[nt] = {bv, bv, bv, bv};
        }
        const uint16_t* bb = tw1seb + (size_t)(wv * 64 + l16) * 256 + quad * 8;
        bf16x8 bc[4], bn[4];
        #pragma unroll
        for (int nt = 0; nt < 4; ++nt)
            bc[nt] = *reinterpret_cast<const bf16x8*>(bb + nt * 4096);
        #pragma unroll
        for (int kk = 0; kk < 8; ++kk) {
            if (kk < 7) {
                #pragma unroll
                for (int nt = 0; nt < 4; ++nt)
                    bn[nt] = *reinterpret_cast<const bf16x8*>(
                        bb + nt * 4096 + (kk + 1) * 32);
            }
            bf16x8 af = *reinterpret_cast<const bf16x8*>(
                &seL[l16 * 264 + kk * 32 + quad * 8]);   // rows 8..15 = zeros
            #pragma unroll
            for (int nt = 0; nt < 4; ++nt)
                acc[nt] = __builtin_amdgcn_mfma_f32_16x16x32_bf16(
                    af, bc[nt], acc[nt], 0, 0, 0);
            #pragma unroll
            for (int nt = 0; nt < 4; ++nt) bc[nt] = bn[nt];
        }
        if (quad < 2) {                                  // rows 0..7 valid
            #pragma unroll
            for (int nt = 0; nt < 4; ++nt)
                #pragma unroll
                for (int r = 0; r < 4; ++r)
                    ws[WCSE + (size_t)(b0 + quad * 4 + r) * 512 +
                       wv * 64 + nt * 16 + l16] = f2u(acc[nt][r]);
        }
    }
}

// ---------------- k_main (identical to R12: 135.4 us) ----------------------
static constexpr int UQB_OFF  = 0;
static constexpr int NOOP_OFF = 5120;
static constexpr int CSE_OFF  = 5376;
static constexpr int H1U_OFF  = 9472;
static constexpr int UET_OFF  = 26880;
static constexpr int H1T_OFF  = 44288;
static constexpr int SMEM_SZ  = 78080;

__global__ __launch_bounds__(512, 4) void k_main(
    const float* __restrict__ obs,
    const float* __restrict__ ub1,
    const float* __restrict__ ub2, const float* __restrict__ emb,
    const float* __restrict__ tb2,
    const float* __restrict__ vw,  const float* __restrict__ vb,
    const float* __restrict__ dw,  const float* __restrict__ db,
    const uint16_t* __restrict__ wsb,
    float* __restrict__ out)
{
    __shared__ __align__(16) char smem[SMEM_SZ];
    uint16_t* uqb   = (uint16_t*)(smem + UQB_OFF);
    float*    noopf = (float*)(smem + NOOP_OFF);
    uint16_t* cseL  = (uint16_t*)(smem + CSE_OFF);
    uint16_t* h1u   = (uint16_t*)(smem + H1U_OFF);
    uint16_t* uet   = (uint16_t*)(smem + UET_OFF);
    uint16_t* h1t   = (uint16_t*)(smem + H1T_OFF);
    uint16_t* t2    = h1t;

    const int t    = threadIdx.x;
    const int wv   = t >> 6;
    const int lane = t & 63;
    const int quad = lane >> 4;
    const int l16  = lane & 15;
    const int b0   = blockIdx.x * 4;

    const uint16_t* csep  = wsb + WCSE;
    const uint16_t* tw1ue = wsb + WTW1UE;
    const uint16_t* tw2b  = wsb + WTW2;
    const uint16_t* uw2b  = wsb + WUW2;
    const uint16_t* uw1b  = wsb + WUW1B;

    // ---- stage 1: uqb bf16 [64][40] (K=32 zero-padded), noop, cse rows ----
    {
        int r = t >> 3, q = t & 7;
        int e = r >> 4, o = r & 15;
        ushort4 ov = {0, 0, 0, 0};
        if (q < 2) {
            const float2* sp = reinterpret_cast<const float2*>(
                &obs[(size_t)(b0 + e) * 150 + 22 + o * 8 + q * 4]);
            float2 a = sp[0], b = sp[1];
            ov.x = f2u(a.x); ov.y = f2u(a.y); ov.z = f2u(b.x); ov.w = f2u(b.y);
        }
        *reinterpret_cast<ushort4*>(&uqb[r * 40 + q * 4]) = ov;
        #pragma unroll
        for (int ii = 0; ii < 2; ++ii) {
            int i = t + ii * 512;
            int ee = i >> 8, cc = i & 255;
            ((uint32_t*)cseL)[ee * 256 + cc] =
                ((const uint32_t*)(csep + (size_t)(b0 + ee) * 512))[cc];
        }
        if (t < 64) {
            int ee = t >> 4, oo = t & 15;
            noopf[t] = (obs[(size_t)(b0 + ee) * 150 + 22 + oo * 8] == 1.0f) ? 1.0f : 0.0f;
        }
    }
    __syncthreads();

    // ---- stage 2: unique L1 via MFMA (wave: M=64 x N=16, K=32) ----
    {
        const int n = wv * 16 + l16;
        const float bv = ub1[n];
        f32x4 acc[4];
        #pragma unroll
        for (int mt = 0; mt < 4; ++mt) acc[mt] = {bv, bv, bv, bv};
        bf16x8 bf = *reinterpret_cast<const bf16x8*>(&uw1b[n * 32 + quad * 8]);
        #pragma unroll
        for (int mt = 0; mt < 4; ++mt) {
            bf16x8 af = *reinterpret_cast<const bf16x8*>(
                &uqb[(mt * 16 + l16) * 40 + quad * 8]);
            acc[mt] = __builtin_amdgcn_mfma_f32_16x16x32_bf16(af, bf, acc[mt], 0, 0, 0);
        }
        #pragma unroll
        for (int mt = 0; mt < 4; ++mt)
            #pragma unroll
            for (int r = 0; r < 4; ++r) {
                int row = mt * 16 + quad * 4 + r;
                h1u[row * 136 + n] = f2u(fmaxf(acc[mt][r], 0.f));
            }
    }
    __syncthreads();

    // ---- stage 3: unique L2 via MFMA (wave: M=64 x N=16), K=128 -> uet ----
    {
        const int n = wv * 16 + l16;
        const float bv = ub2[n];
        const float ev = emb[n];
        f32x4 acc[4];
        #pragma unroll
        for (int mt = 0; mt < 4; ++mt) acc[mt] = {bv, bv, bv, bv};
        #pragma unroll
        for (int kk = 0; kk < 4; ++kk) {
            bf16x8 bf = *reinterpret_cast<const bf16x8*>(
                &uw2b[(size_t)n * 128 + kk * 32 + quad * 8]);
            #pragma unroll
            for (int mt = 0; mt < 4; ++mt) {
                bf16x8 af = *reinterpret_cast<const bf16x8*>(
                    &h1u[(mt * 16 + l16) * 136 + kk * 32 + quad * 8]);
                acc[mt] = __builtin_amdgcn_mfma_f32_16x16x32_bf16(af, bf, acc[mt], 0, 0, 0);
            }
        }
        #pragma unroll
        for (int mt = 0; mt < 4; ++mt)
            #pragma unroll
            for (int r = 0; r < 4; ++r) {
                int row = mt * 16 + quad * 4 + r;
                float v = (noopf[row] != 0.0f) ? ev : fmaxf(acc[mt][r], 0.f);
                uet[row * 136 + n] = f2u(v);
            }
    }
    __syncthreads();

    // ---- trunk: 2 N-chunks of 256; L1 (K=128, acc init = cse) -> L2 ----
    f32x4 acc2[4][2];
    #pragma unroll
    for (int nt = 0; nt < 2; ++nt) {
        float bv = tb2[wv * 32 + nt * 16 + l16];
        #pragma unroll
        for (int mt = 0; mt < 4; ++mt) acc2[mt][nt] = {bv, bv, bv, bv};
    }

    #pragma unroll
    for (int nc = 0; nc < 2; ++nc) {
        {
            f32x4 acc1[4][2];
            #pragma unroll
            for (int nt = 0; nt < 2; ++nt) {
                int n = nc * 256 + wv * 32 + nt * 16 + l16;
                #pragma unroll
                for (int mt = 0; mt < 4; ++mt) {
                    float v = u2f(cseL[mt * 512 + n]);
                    acc1[mt][nt] = {v, v, v, v};
                }
            }
            const uint16_t* bb = tw1ue + (size_t)(nc * 256 + wv * 32 + l16) * 128
                                 + quad * 8;
            bf16x8 bc[2], bn[2];
            bc[0] = *reinterpret_cast<const bf16x8*>(bb);
            bc[1] = *reinterpret_cast<const bf16x8*>(bb + 2048);
            #pragma unroll
            for (int kk = 0; kk < 4; ++kk) {
                if (kk < 3) {
                    bn[0] = *reinterpret_cast<const bf16x8*>(bb + (kk + 1) * 32);
                    bn[1] = *reinterpret_cast<const bf16x8*>(bb + 2048 + (kk + 1) * 32);
                }
                bf16x8 af[4];
                #pragma unroll
                for (int mt = 0; mt < 4; ++mt)
                    af[mt] = *reinterpret_cast<const bf16x8*>(
                        &uet[(mt * 16 + l16) * 136 + kk * 32 + quad * 8]);
                #pragma unroll
                for (int mt = 0; mt < 4; ++mt)
                    #pragma unroll
                    for (int nt = 0; nt < 2; ++nt)
                        acc1[mt][nt] = __builtin_amdgcn_mfma_f32_16x16x32_bf16(
                            af[mt], bc[nt], acc1[mt][nt], 0, 0, 0);
                bc[0] = bn[0]; bc[1] = bn[1];
            }
            #pragma unroll
            for (int mt = 0; mt < 4; ++mt)
                #pragma unroll
                for (int nt = 0; nt < 2; ++nt)
                    #pragma unroll
                    for (int r = 0; r < 4; ++r) {
                        int row = mt * 16 + quad * 4 + r;
                        h1t[row * 264 + wv * 32 + nt * 16 + l16] =
                            f2u(fmaxf(acc1[mt][nt][r], 0.f));
                    }
        }
        __syncthreads();
        {
            const uint16_t* cb = tw2b + (size_t)(wv * 32 + l16) * 512 + nc * 256
                                 + quad * 8;
            bf16x8 cc[2], cn[2];
            cc[0] = *reinterpret_cast<const bf16x8*>(cb);
            cc[1] = *reinterpret_cast<const bf16x8*>(cb + 8192);
            #pragma unroll
            for (int k2 = 0; k2 < 8; ++k2) {
                if (k2 < 7) {
                    cn[0] = *reinterpret_cast<const bf16x8*>(cb + (k2 + 1) * 32);
                    cn[1] = *reinterpret_cast<const bf16x8*>(cb + 8192 + (k2 + 1) * 32);
                }
                bf16x8 af[4];
                #pragma unroll
                for (int mt = 0; mt < 4; ++mt)
                    af[mt] = *reinterpret_cast<const bf16x8*>(
                        &h1t[(mt * 16 + l16) * 264 + k2 * 32 + quad * 8]);
                #pragma unroll
                for (int mt = 0; mt < 4; ++mt)
                    #pragma unroll
                    for (int nt = 0; nt < 2; ++nt)
                        acc2[mt][nt] = __builtin_amdgcn_mfma_f32_16x16x32_bf16(
                            af[mt], cc[nt], acc2[mt][nt], 0, 0, 0);
                cc[0] = cn[0]; cc[1] = cn[1];
            }
        }
        if (nc == 0) __syncthreads();
    }
    __syncthreads();
    #pragma unroll
    for (int mt = 0; mt < 4; ++mt)
        #pragma unroll
        for (int nt = 0; nt < 2; ++nt)
            #pragma unroll
            for (int r = 0; r < 4; ++r) {
                int row = mt * 16 + quad * 4 + r;
                t2[row * 264 + wv * 32 + nt * 16 + l16] =
                    f2u(fmaxf(acc2[mt][nt][r], 0.f));
            }
    __syncthreads();

    // ---- heads ----
    {
        float vwf[4], dwf[4];
        #pragma unroll
        for (int j = 0; j < 4; ++j) {
            vwf[j] = vw[lane + 64 * j];
            dwf[j] = dw[lane + 64 * j];
        }
        const float vbf = vb[0], dbf = db[0];
        #pragma unroll
        for (int rr = 0; rr < 8; ++rr) {
            int row = wv * 8 + rr;
            float sv = 0.f, sd = 0.f;
            #pragma unroll
            for (int j = 0; j < 4; ++j) {
                float tv = u2f(t2[row * 264 + lane + 64 * j]);
                sv += tv * vwf[j];
                sd += tv * dwf[j];
            }
            #pragma unroll
            for (int off = 32; off > 0; off >>= 1) {
                sv += __shfl_down(sv, off);
                sd += __shfl_down(sd, off);
            }
            if (lane == 0) {
                int g = blockIdx.x * 64 + row;
                out[g] = sv + vbf;
                float z = sd + dbf;
                float sig = 1.f / (1.f + __expf(-z));
                out[B_ * 16 + g] = sig * 0.4f + 0.1f;
            }
        }
    }
}

extern "C" void kernel_launch(void* const* d_in, const int* in_sizes, int n_in,
                              void* d_out, int out_size, void* d_ws, size_t ws_size,
                              hipStream_t stream) {
    const float* obs = (const float*)d_in[0];
    const float* sw1 = (const float*)d_in[1];
    const float* sb1 = (const float*)d_in[2];
    const float* sw2 = (const float*)d_in[3];
    const float* sb2 = (const float*)d_in[4];
    const float* uw1 = (const float*)d_in[5];
    const float* ub1 = (const float*)d_in[6];
    const float* uw2 = (const float*)d_in[7];
    const float* ub2 = (const float*)d_in[8];
    const float* emb = (const float*)d_in[9];
    const float* tw1 = (const float*)d_in[10];
    const float* tb1 = (const float*)d_in[11];
    const float* tw2 = (const float*)d_in[12];
    const float* tb2 = (const float*)d_in[13];
    const float* vw  = (const float*)d_in[14];
    const float* vb  = (const float*)d_in[15];
    const float* dw  = (const float*)d_in[16];
    const float* db  = (const float*)d_in[17];

    uint16_t* wsb = (uint16_t*)d_ws;

    k_conv<<<404, 256, 0, stream>>>(tw1, tw2, uw2, sw2, uw1, wsb);
    k_cse<<<1024, 512, 0, stream>>>(obs, sw1, sb1, sb2, tb1, wsb);
    k_main<<<B_ / 4, 512, 0, stream>>>(obs, ub1, ub2, emb, tb2,
                                       vw, vb, dw, db, wsb, (float*)d_out);
}

// Round 17
// 237.560 us; speedup vs baseline: 1.0983x; 1.0983x over previous
//
#include <hip/hip_runtime.h>
#include <stdint.h>

// GaitnetActor B=8192, OPT=16. Round 17: exact restore of R12 — the best
// measured configuration (239.5 us total; k_main 135.4 us in that session,
// 135-148 across sessions = noise band). Structure: k_conv (weights->bf16),
// k_cse (cse[b]=se[b]@W1se^T+tb1, M=16/block, 512 blocks), k_main (M=64,
// 512 thr, 2 blocks/CU, trunk-L1 K=128 ue-part with acc init = cse,
// K-chunk-fused trunk-L2). bf16 MFMA / fp32 accum.
// out[0:131072]=logits fp32, [131072:262144]=duration fp32.

static constexpr int B_ = 8192;

typedef __attribute__((ext_vector_type(8))) short bf16x8;
typedef __attribute__((ext_vector_type(4))) float f32x4;

__device__ __forceinline__ float u2f(uint16_t u) {
    union { uint32_t i; float f; } c; c.i = (uint32_t)u << 16; return c.f;
}
__device__ __forceinline__ uint16_t f2u(float f) {
    union { float f; uint32_t i; } c; c.f = f;
    uint32_t x = c.i;
    return (uint16_t)((x + 0x7FFFu + ((x >> 16) & 1u)) >> 16);
}

// ws layout (uint16 elems)
static constexpr size_t WCSE   = 0;                    // bf16 [8192][512]
static constexpr size_t WTW1SE = 4194304;              // bf16 [512][256]
static constexpr size_t WTW1UE = WTW1SE + 131072;      // bf16 [512][128]
static constexpr size_t WTW2   = WTW1UE + 65536;       // bf16 [256][512]
static constexpr size_t WUW2   = WTW2 + 131072;        // bf16 [128][128]
static constexpr size_t WSW2   = WUW2 + 16384;         // bf16 [256][256]
static constexpr size_t WUW1B  = WSW2 + 65536;         // bf16 [128][32] 0-pad

// ---------------- k_conv: all weights fp32 -> bf16 (404 blocks) ------------
__global__ __launch_bounds__(256) void k_conv(
    const float* __restrict__ tw1, const float* __restrict__ tw2,
    const float* __restrict__ uw2, const float* __restrict__ sw2,
    const float* __restrict__ uw1, uint16_t* __restrict__ ws)
{
    int i4 = blockIdx.x * 256 + threadIdx.x;
    if (i4 >= 102400) {                          // uw1b: zero-padded K=32
        int q = i4 - 102400;                     // [0,1024)
        int n = q >> 3, k0 = (q & 7) * 4;
        ushort4 o = {0, 0, 0, 0};
        if (k0 < 8) {
            float4 v = *reinterpret_cast<const float4*>(uw1 + n * 8 + k0);
            o.x = f2u(v.x); o.y = f2u(v.y); o.z = f2u(v.z); o.w = f2u(v.w);
        }
        *reinterpret_cast<ushort4*>(ws + WUW1B + n * 32 + k0) = o;
        return;
    }
    const float* src; size_t dst;
    if (i4 < 32768) {                            // tw1 se-part (k<256)
        int g = i4 * 4, n = g >> 8, k = g & 255;
        src = tw1 + (size_t)n * 384 + k;
        dst = WTW1SE + (size_t)g;
    } else if (i4 < 49152) {                     // tw1 ue-part (k>=256)
        int q = i4 - 32768, n = q >> 5, w = q & 31;
        src = tw1 + (size_t)n * 384 + 256 + w * 4;
        dst = WTW1UE + (size_t)n * 128 + w * 4;
    } else if (i4 < 81920) {
        int q = (i4 - 49152) * 4;
        src = tw2 + q; dst = WTW2 + q;
    } else if (i4 < 86016) {
        int q = (i4 - 81920) * 4;
        src = uw2 + q; dst = WUW2 + q;
    } else {
        int q = (i4 - 86016) * 4;
        src = sw2 + q; dst = WSW2 + q;
    }
    float4 v = *reinterpret_cast<const float4*>(src);
    ushort4 o;
    o.x = f2u(v.x); o.y = f2u(v.y); o.z = f2u(v.z); o.w = f2u(v.w);
    *reinterpret_cast<ushort4*>(ws + dst) = o;
}

// ---------------- k_cse: se + cse, 16 elems/block, 512 thr (512 blocks) ----
__global__ __launch_bounds__(512) void k_cse(
    const float* __restrict__ obs,
    const float* __restrict__ sw1, const float* __restrict__ sb1,
    const float* __restrict__ sb2, const float* __restrict__ tb1,
    uint16_t* __restrict__ ws)
{
    __shared__ float xs[16][24];
    __shared__ uint16_t h1s[16 * 264];
    __shared__ uint16_t seL[16 * 264];
    const int t = threadIdx.x;
    const int b0 = blockIdx.x * 16;
    const uint16_t* sw2b   = ws + WSW2;
    const uint16_t* tw1seb = ws + WTW1SE;

    if (t < 352) {
        int e = t / 22, c = t - e * 22;
        xs[e][c] = obs[(size_t)(b0 + e) * 150 + c];
    }
    __syncthreads();
    {   // shared L1 (VALU): neuron t&255, 8 elems each
        const int n = t & 255;
        float w[22];
        #pragma unroll
        for (int k = 0; k < 22; ++k) w[k] = sw1[n * 22 + k];
        const float bias = sb1[n];
        #pragma unroll
        for (int ii = 0; ii < 8; ++ii) {
            int e = (t >> 8) * 8 + ii;
            float a = bias;
            #pragma unroll
            for (int k = 0; k < 22; ++k) a += w[k] * xs[e][k];
            h1s[e * 264 + n] = f2u(fmaxf(a, 0.f));
        }
    }
    __syncthreads();
    const int wv = t >> 6, lane = t & 63, quad = lane >> 4, l16 = lane & 15;
    {   // shared L2 (MFMA): M=16, wave N=32, K=256 -> seL
        f32x4 acc[2];
        #pragma unroll
        for (int nt = 0; nt < 2; ++nt) {
            float bv = sb2[wv * 32 + nt * 16 + l16];
            acc[nt] = {bv, bv, bv, bv};
        }
        const uint16_t* bb = sw2b + (size_t)(wv * 32 + l16) * 256 + quad * 8;
        bf16x8 bc[2], bn[2];
        bc[0] = *reinterpret_cast<const bf16x8*>(bb);
        bc[1] = *reinterpret_cast<const bf16x8*>(bb + 4096);
        #pragma unroll
        for (int kk = 0; kk < 8; ++kk) {
            if (kk < 7) {
                bn[0] = *reinterpret_cast<const bf16x8*>(bb + (kk + 1) * 32);
                bn[1] = *reinterpret_cast<const bf16x8*>(bb + 4096 + (kk + 1) * 32);
            }
            bf16x8 af = *reinterpret_cast<const bf16x8*>(
                &h1s[l16 * 264 + kk * 32 + quad * 8]);
            #pragma unroll
            for (int nt = 0; nt < 2; ++nt)
                acc[nt] = __builtin_amdgcn_mfma_f32_16x16x32_bf16(
                    af, bc[nt], acc[nt], 0, 0, 0);
            bc[0] = bn[0]; bc[1] = bn[1];
        }
        #pragma unroll
        for (int nt = 0; nt < 2; ++nt)
            #pragma unroll
            for (int r = 0; r < 4; ++r)
                seL[(quad * 4 + r) * 264 + wv * 32 + nt * 16 + l16] =
                    f2u(fmaxf(acc[nt][r], 0.f));
    }
    __syncthreads();
    {   // cse (MFMA): M=16, wave N=64, K=256, no relu -> ws
        f32x4 acc[4];
        #pragma unroll
        for (int nt = 0; nt < 4; ++nt) {
            float bv = tb1[wv * 64 + nt * 16 + l16];
            acc[nt] = {bv, bv, bv, bv};
        }
        const uint16_t* bb = tw1seb + (size_t)(wv * 64 + l16) * 256 + quad * 8;
        bf16x8 bc[4], bn[4];
        #pragma unroll
        for (int nt = 0; nt < 4; ++nt)
            bc[nt] = *reinterpret_cast<const bf16x8*>(bb + nt * 4096);
        #pragma unroll
        for (int kk = 0; kk < 8; ++kk) {
            if (kk < 7) {
                #pragma unroll
                for (int nt = 0; nt < 4; ++nt)
                    bn[nt] = *reinterpret_cast<const bf16x8*>(
                        bb + nt * 4096 + (kk + 1) * 32);
            }
            bf16x8 af = *reinterpret_cast<const bf16x8*>(
                &seL[l16 * 264 + kk * 32 + quad * 8]);
            #pragma unroll
            for (int nt = 0; nt < 4; ++nt)
                acc[nt] = __builtin_amdgcn_mfma_f32_16x16x32_bf16(
                    af, bc[nt], acc[nt], 0, 0, 0);
            #pragma unroll
            for (int nt = 0; nt < 4; ++nt) bc[nt] = bn[nt];
        }
        #pragma unroll
        for (int nt = 0; nt < 4; ++nt)
            #pragma unroll
            for (int r = 0; r < 4; ++r)
                ws[WCSE + (size_t)(b0 + quad * 4 + r) * 512 +
                   wv * 64 + nt * 16 + l16] = f2u(acc[nt][r]);
    }
}

// ---------------- k_main -------------------------------------------------
// LDS (bytes): uqb bf16[64][40] 0..5120 | noop f32[64] @5120 | cse bf16[4][512]
// @5376 | h1u bf16[64][136] @9472 | uet @26880 | h1t bf16[64][264] @44288
// (t2 overlays) -> 78080 B, 2 blocks/CU.
static constexpr int UQB_OFF  = 0;
static constexpr int NOOP_OFF = 5120;
static constexpr int CSE_OFF  = 5376;
static constexpr int H1U_OFF  = 9472;
static constexpr int UET_OFF  = 26880;
static constexpr int H1T_OFF  = 44288;
static constexpr int SMEM_SZ  = 78080;

__global__ __launch_bounds__(512, 4) void k_main(
    const float* __restrict__ obs,
    const float* __restrict__ ub1,
    const float* __restrict__ ub2, const float* __restrict__ emb,
    const float* __restrict__ tb2,
    const float* __restrict__ vw,  const float* __restrict__ vb,
    const float* __restrict__ dw,  const float* __restrict__ db,
    const uint16_t* __restrict__ wsb,
    float* __restrict__ out)
{
    __shared__ __align__(16) char smem[SMEM_SZ];
    uint16_t* uqb   = (uint16_t*)(smem + UQB_OFF);
    float*    noopf = (float*)(smem + NOOP_OFF);
    uint16_t* cseL  = (uint16_t*)(smem + CSE_OFF);
    uint16_t* h1u   = (uint16_t*)(smem + H1U_OFF);
    uint16_t* uet   = (uint16_t*)(smem + UET_OFF);
    uint16_t* h1t   = (uint16_t*)(smem + H1T_OFF);
    uint16_t* t2    = h1t;

    const int t    = threadIdx.x;
    const int wv   = t >> 6;
    const int lane = t & 63;
    const int quad = lane >> 4;
    const int l16  = lane & 15;
    const int b0   = blockIdx.x * 4;

    const uint16_t* csep  = wsb + WCSE;
    const uint16_t* tw1ue = wsb + WTW1UE;
    const uint16_t* tw2b  = wsb + WTW2;
    const uint16_t* uw2b  = wsb + WUW2;
    const uint16_t* uw1b  = wsb + WUW1B;

    // ---- stage 1: uqb bf16 [64][40] (K=32 zero-padded), noop, cse rows ----
    {
        int r = t >> 3, q = t & 7;               // row 0..63, k-quad 0..7
        int e = r >> 4, o = r & 15;
        ushort4 ov = {0, 0, 0, 0};
        if (q < 2) {                             // cols 0..7 real (8B-aligned)
            const float2* sp = reinterpret_cast<const float2*>(
                &obs[(size_t)(b0 + e) * 150 + 22 + o * 8 + q * 4]);
            float2 a = sp[0], b = sp[1];
            ov.x = f2u(a.x); ov.y = f2u(a.y); ov.z = f2u(b.x); ov.w = f2u(b.y);
        }
        *reinterpret_cast<ushort4*>(&uqb[r * 40 + q * 4]) = ov;
        #pragma unroll
        for (int ii = 0; ii < 2; ++ii) {         // cse rows: 1024 dwords
            int i = t + ii * 512;
            int ee = i >> 8, cc = i & 255;
            ((uint32_t*)cseL)[ee * 256 + cc] =
                ((const uint32_t*)(csep + (size_t)(b0 + ee) * 512))[cc];
        }
        if (t < 64) {
            int ee = t >> 4, oo = t & 15;
            noopf[t] = (obs[(size_t)(b0 + ee) * 150 + 22 + oo * 8] == 1.0f) ? 1.0f : 0.0f;
        }
    }
    __syncthreads();

    // ---- stage 2: unique L1 via MFMA (wave: M=64 x N=16, K=32) ----
    {
        const int n = wv * 16 + l16;
        const float bv = ub1[n];
        f32x4 acc[4];
        #pragma unroll
        for (int mt = 0; mt < 4; ++mt) acc[mt] = {bv, bv, bv, bv};
        bf16x8 bf = *reinterpret_cast<const bf16x8*>(&uw1b[n * 32 + quad * 8]);
        #pragma unroll
        for (int mt = 0; mt < 4; ++mt) {
            bf16x8 af = *reinterpret_cast<const bf16x8*>(
                &uqb[(mt * 16 + l16) * 40 + quad * 8]);
            acc[mt] = __builtin_amdgcn_mfma_f32_16x16x32_bf16(af, bf, acc[mt], 0, 0, 0);
        }
        #pragma unroll
        for (int mt = 0; mt < 4; ++mt)
            #pragma unroll
            for (int r = 0; r < 4; ++r) {
                int row = mt * 16 + quad * 4 + r;
                h1u[row * 136 + n] = f2u(fmaxf(acc[mt][r], 0.f));
            }
    }
    __syncthreads();

    // ---- stage 3: unique L2 via MFMA (wave: M=64 x N=16), K=128 -> uet ----
    {
        const int n = wv * 16 + l16;
        const float bv = ub2[n];
        const float ev = emb[n];
        f32x4 acc[4];
        #pragma unroll
        for (int mt = 0; mt < 4; ++mt) acc[mt] = {bv, bv, bv, bv};
        #pragma unroll
        for (int kk = 0; kk < 4; ++kk) {
            bf16x8 bf = *reinterpret_cast<const bf16x8*>(
                &uw2b[(size_t)n * 128 + kk * 32 + quad * 8]);
            #pragma unroll
            for (int mt = 0; mt < 4; ++mt) {
                bf16x8 af = *reinterpret_cast<const bf16x8*>(
                    &h1u[(mt * 16 + l16) * 136 + kk * 32 + quad * 8]);
                acc[mt] = __builtin_amdgcn_mfma_f32_16x16x32_bf16(af, bf, acc[mt], 0, 0, 0);
            }
        }
        #pragma unroll
        for (int mt = 0; mt < 4; ++mt)
            #pragma unroll
            for (int r = 0; r < 4; ++r) {
                int row = mt * 16 + quad * 4 + r;
                float v = (noopf[row] != 0.0f) ? ev : fmaxf(acc[mt][r], 0.f);
                uet[row * 136 + n] = f2u(v);
            }
    }
    __syncthreads();

    // ---- trunk: 2 N-chunks of 256; L1 (K=128, acc init = cse) -> L2 ----
    f32x4 acc2[4][2];
    #pragma unroll
    for (int nt = 0; nt < 2; ++nt) {
        float bv = tb2[wv * 32 + nt * 16 + l16];
        #pragma unroll
        for (int mt = 0; mt < 4; ++mt) acc2[mt][nt] = {bv, bv, bv, bv};
    }

    #pragma unroll
    for (int nc = 0; nc < 2; ++nc) {
        {
            f32x4 acc1[4][2];
            #pragma unroll
            for (int nt = 0; nt < 2; ++nt) {
                int n = nc * 256 + wv * 32 + nt * 16 + l16;
                #pragma unroll
                for (int mt = 0; mt < 4; ++mt) {
                    float v = u2f(cseL[mt * 512 + n]);
                    acc1[mt][nt] = {v, v, v, v};
                }
            }
            const uint16_t* bb = tw1ue + (size_t)(nc * 256 + wv * 32 + l16) * 128
                                 + quad * 8;
            bf16x8 bc[2], bn[2];
            bc[0] = *reinterpret_cast<const bf16x8*>(bb);
            bc[1] = *reinterpret_cast<const bf16x8*>(bb + 2048);
            #pragma unroll
            for (int kk = 0; kk < 4; ++kk) {
                if (kk < 3) {
                    bn[0] = *reinterpret_cast<const bf16x8*>(bb + (kk + 1) * 32);
                    bn[1] = *reinterpret_cast<const bf16x8*>(bb + 2048 + (kk + 1) * 32);
                }
                bf16x8 af[4];
                #pragma unroll
                for (int mt = 0; mt < 4; ++mt)
                    af[mt] = *reinterpret_cast<const bf16x8*>(
                        &uet[(mt * 16 + l16) * 136 + kk * 32 + quad * 8]);
                #pragma unroll
                for (int mt = 0; mt < 4; ++mt)
                    #pragma unroll
                    for (int nt = 0; nt < 2; ++nt)
                        acc1[mt][nt] = __builtin_amdgcn_mfma_f32_16x16x32_bf16(
                            af[mt], bc[nt], acc1[mt][nt], 0, 0, 0);
                bc[0] = bn[0]; bc[1] = bn[1];
            }
            #pragma unroll
            for (int mt = 0; mt < 4; ++mt)
                #pragma unroll
                for (int nt = 0; nt < 2; ++nt)
                    #pragma unroll
                    for (int r = 0; r < 4; ++r) {
                        int row = mt * 16 + quad * 4 + r;
                        h1t[row * 264 + wv * 32 + nt * 16 + l16] =
                            f2u(fmaxf(acc1[mt][nt][r], 0.f));
                    }
        }
        __syncthreads();
        {
            const uint16_t* cb = tw2b + (size_t)(wv * 32 + l16) * 512 + nc * 256
                                 + quad * 8;
            bf16x8 cc[2], cn[2];
            cc[0] = *reinterpret_cast<const bf16x8*>(cb);
            cc[1] = *reinterpret_cast<const bf16x8*>(cb + 8192);
            #pragma unroll
            for (int k2 = 0; k2 < 8; ++k2) {
                if (k2 < 7) {
                    cn[0] = *reinterpret_cast<const bf16x8*>(cb + (k2 + 1) * 32);
                    cn[1] = *reinterpret_cast<const bf16x8*>(cb + 8192 + (k2 + 1) * 32);
                }
                bf16x8 af[4];
                #pragma unroll
                for (int mt = 0; mt < 4; ++mt)
                    af[mt] = *reinterpret_cast<const bf16x8*>(
                        &h1t[(mt * 16 + l16) * 264 + k2 * 32 + quad * 8]);
                #pragma unroll
                for (int mt = 0; mt < 4; ++mt)
                    #pragma unroll
                    for (int nt = 0; nt < 2; ++nt)
                        acc2[mt][nt] = __builtin_amdgcn_mfma_f32_16x16x32_bf16(
                            af[mt], cc[nt], acc2[mt][nt], 0, 0, 0);
                cc[0] = cn[0]; cc[1] = cn[1];
            }
        }
        if (nc == 0) __syncthreads();
    }
    __syncthreads();
    #pragma unroll
    for (int mt = 0; mt < 4; ++mt)
        #pragma unroll
        for (int nt = 0; nt < 2; ++nt)
            #pragma unroll
            for (int r = 0; r < 4; ++r) {
                int row = mt * 16 + quad * 4 + r;
                t2[row * 264 + wv * 32 + nt * 16 + l16] =
                    f2u(fmaxf(acc2[mt][nt][r], 0.f));
            }
    __syncthreads();

    // ---- heads ----
    {
        float vwf[4], dwf[4];
        #pragma unroll
        for (int j = 0; j < 4; ++j) {
            vwf[j] = vw[lane + 64 * j];
            dwf[j] = dw[lane + 64 * j];
        }
        const float vbf = vb[0], dbf = db[0];
        #pragma unroll
        for (int rr = 0; rr < 8; ++rr) {
            int row = wv * 8 + rr;
            float sv = 0.f, sd = 0.f;
            #pragma unroll
            for (int j = 0; j < 4; ++j) {
                float tv = u2f(t2[row * 264 + lane + 64 * j]);
                sv += tv * vwf[j];
                sd += tv * dwf[j];
            }
            #pragma unroll
            for (int off = 32; off > 0; off >>= 1) {
                sv += __shfl_down(sv, off);
                sd += __shfl_down(sd, off);
            }
            if (lane == 0) {
                int g = blockIdx.x * 64 + row;
                out[g] = sv + vbf;
                float z = sd + dbf;
                float sig = 1.f / (1.f + __expf(-z));
                out[B_ * 16 + g] = sig * 0.4f + 0.1f;
            }
        }
    }
}

extern "C" void kernel_launch(void* const* d_in, const int* in_sizes, int n_in,
                              void* d_out, int out_size, void* d_ws, size_t ws_size,
                              hipStream_t stream) {
    const float* obs = (const float*)d_in[0];
    const float* sw1 = (const float*)d_in[1];
    const float* sb1 = (const float*)d_in[2];
    const float* sw2 = (const float*)d_in[3];
    const float* sb2 = (const float*)d_in[4];
    const float* uw1 = (const float*)d_in[5];
    const float* ub1 = (const float*)d_in[6];
    const float* uw2 = (const float*)d_in[7];
    const float* ub2 = (const float*)d_in[8];
    const float* emb = (const float*)d_in[9];
    const float* tw1 = (const float*)d_in[10];
    const float* tb1 = (const float*)d_in[11];
    const float* tw2 = (const float*)d_in[12];
    const float* tb2 = (const float*)d_in[13];
    const float* vw  = (const float*)d_in[14];
    const float* vb  = (const float*)d_in[15];
    const float* dw  = (const float*)d_in[16];
    const float* db  = (const float*)d_in[17];

    uint16_t* wsb = (uint16_t*)d_ws;

    k_conv<<<404, 256, 0, stream>>>(tw1, tw2, uw2, sw2, uw1, wsb);
    k_cse<<<512, 512, 0, stream>>>(obs, sw1, sb1, sb2, tb1, wsb);
    k_main<<<B_ / 4, 512, 0, stream>>>(obs, ub1, ub2, emb, tb2,
                                       vw, vb, dw, db, wsb, (float*)d_out);
}